// Round 1
// baseline (1603.536 us; speedup 1.0000x reference)
//
#include <hip/hip_runtime.h>

#define D 128
#define D4 32   // floats4 per row
#define ZSTRIDE 132  // padded LDS stride for z tile (breaks bank conflicts)

// ---------------- scatter-add: aggr[dst] += x[src] ----------------
__global__ __launch_bounds__(256) void scatter_kernel(
    const float4* __restrict__ x4, const int* __restrict__ ei,
    float* __restrict__ aggr, int E, int total)
{
    int i = blockIdx.x * 256 + threadIdx.x;
    if (i >= total) return;
    int e = i >> 5;           // edge id
    int g = i & 31;           // float4 group within row
    int src = ei[e];
    int dst = ei[E + e];
    float4 v = x4[(size_t)src * D4 + g];
    float* p = aggr + (size_t)dst * D + g * 4;
    atomicAdd(p + 0, v.x);
    atomicAdd(p + 1, v.y);
    atomicAdd(p + 2, v.z);
    atomicAdd(p + 3, v.w);
}

// ---------------- fused GEMM + BN-stat accumulation ----------------
// mode 0: in = (1+eps)*x + aggr          (in0=x, in1=aggr, epsp valid)
// mode 1: in = relu(z1*sc[k] + sh[k])    (in0=z1, sc/sh valid)
// z = in @ W + bias ; writes z to zout; accumulates per-column sum/sumsq.
__global__ __launch_bounds__(256) void gemm_bn_kernel(
    const float* __restrict__ in0,
    const float* __restrict__ in1,
    const float* __restrict__ epsp,
    const float* __restrict__ sc,
    const float* __restrict__ sh,
    const float* __restrict__ W,
    const float* __restrict__ bias,
    float* __restrict__ zout,
    float* __restrict__ stat_sum, float* __restrict__ stat_sq,
    int N, int mode)
{
    __shared__ float Wl[D * D];   // 64 KB exactly
    int tid = threadIdx.x;

    // cooperative W load (float4)
    float4* Wl4 = (float4*)Wl;
    const float4* W4 = (const float4*)W;
    #pragma unroll
    for (int i = 0; i < 16; ++i) Wl4[tid + i * 256] = W4[tid + i * 256];
    __syncthreads();

    int rloc = tid >> 2;              // 0..63
    int r = blockIdx.x * 64 + rloc;   // global row
    int cg = tid & 3;                 // column group 0..3
    int c0 = cg * 32;

    float acc[32];
    #pragma unroll
    for (int j = 0; j < 32; ++j) acc[j] = bias[c0 + j];

    bool valid = (r < N);
    if (valid) {
        const float4* row0 = (const float4*)(in0 + (size_t)r * D);
        const float4* row1 = (const float4*)((in1 ? in1 : in0) + (size_t)r * D);
        float epsv = (mode == 0) ? (1.0f + __ldg(epsp)) : 0.0f;

        for (int kk = 0; kk < D; kk += 16) {
            float a[16];
            #pragma unroll
            for (int q = 0; q < 4; ++q) {
                float4 v = row0[(kk >> 2) + q];
                if (mode == 0) {
                    float4 u = row1[(kk >> 2) + q];
                    v.x = fmaf(epsv, v.x, u.x);
                    v.y = fmaf(epsv, v.y, u.y);
                    v.z = fmaf(epsv, v.z, u.z);
                    v.w = fmaf(epsv, v.w, u.w);
                } else {
                    int c = kk + q * 4;
                    v.x = fmaxf(fmaf(v.x, __ldg(sc + c + 0), __ldg(sh + c + 0)), 0.f);
                    v.y = fmaxf(fmaf(v.y, __ldg(sc + c + 1), __ldg(sh + c + 1)), 0.f);
                    v.z = fmaxf(fmaf(v.z, __ldg(sc + c + 2), __ldg(sh + c + 2)), 0.f);
                    v.w = fmaxf(fmaf(v.w, __ldg(sc + c + 3), __ldg(sh + c + 3)), 0.f);
                }
                a[q * 4 + 0] = v.x; a[q * 4 + 1] = v.y;
                a[q * 4 + 2] = v.z; a[q * 4 + 3] = v.w;
            }
            #pragma unroll
            for (int k2 = 0; k2 < 16; ++k2) {
                float av = a[k2];
                const float4* wrow = Wl4 + (kk + k2) * D4 + cg * 8;
                #pragma unroll
                for (int j8 = 0; j8 < 8; ++j8) {
                    float4 w = wrow[j8];
                    acc[j8 * 4 + 0] = fmaf(av, w.x, acc[j8 * 4 + 0]);
                    acc[j8 * 4 + 1] = fmaf(av, w.y, acc[j8 * 4 + 1]);
                    acc[j8 * 4 + 2] = fmaf(av, w.z, acc[j8 * 4 + 2]);
                    acc[j8 * 4 + 3] = fmaf(av, w.w, acc[j8 * 4 + 3]);
                }
            }
        }
    }

    __syncthreads();            // done reading Wl — reuse as z tile
    float* zl = Wl;             // 64 x ZSTRIDE floats = 33.8 KB < 64 KB

    if (valid) {
        float4* zrow = (float4*)(zout + (size_t)r * D);
        #pragma unroll
        for (int j8 = 0; j8 < 8; ++j8) {
            float4 v = make_float4(acc[j8 * 4 + 0], acc[j8 * 4 + 1],
                                   acc[j8 * 4 + 2], acc[j8 * 4 + 3]);
            zrow[cg * 8 + j8] = v;
            *((float4*)&zl[rloc * ZSTRIDE + c0 + j8 * 4]) = v;
        }
    }
    __syncthreads();

    if (tid < D) {
        int rows = N - blockIdx.x * 64;
        if (rows > 64) rows = 64;
        float s = 0.f, q = 0.f;
        for (int rr = 0; rr < rows; ++rr) {
            float v = zl[rr * ZSTRIDE + tid];
            s += v;
            q = fmaf(v, v, q);
        }
        atomicAdd(&stat_sum[tid], s);
        atomicAdd(&stat_sq[tid], q);
    }
}

// ---------------- BN finalize: scale/shift from sums ----------------
__global__ void bn_finalize_kernel(
    const float* __restrict__ stat_sum, const float* __restrict__ stat_sq,
    const float* __restrict__ gamma, const float* __restrict__ beta,
    float* __restrict__ s_out, float* __restrict__ t_out, float invN)
{
    int c = threadIdx.x;
    float mean = stat_sum[c] * invN;
    float var  = stat_sq[c] * invN - mean * mean;
    float s = gamma[c] * rsqrtf(var + 1e-5f);
    s_out[c] = s;
    t_out[c] = fmaf(-mean, s, beta[c]);
}

// ---------------- final BN + ReLU elementwise ----------------
__global__ __launch_bounds__(256) void bn_relu_kernel(
    const float4* __restrict__ z, float4* __restrict__ out,
    const float* __restrict__ s, const float* __restrict__ t, int total4)
{
    int i = blockIdx.x * 256 + threadIdx.x;
    if (i >= total4) return;
    float4 v = z[i];
    int c = (i & 31) * 4;
    float4 o;
    o.x = fmaxf(fmaf(v.x, s[c + 0], t[c + 0]), 0.f);
    o.y = fmaxf(fmaf(v.y, s[c + 1], t[c + 1]), 0.f);
    o.z = fmaxf(fmaf(v.z, s[c + 2], t[c + 2]), 0.f);
    o.w = fmaxf(fmaf(v.w, s[c + 3], t[c + 3]), 0.f);
    out[i] = o;
}

extern "C" void kernel_launch(void* const* d_in, const int* in_sizes, int n_in,
                              void* d_out, int out_size, void* d_ws, size_t ws_size,
                              hipStream_t stream)
{
    const float* x   = (const float*)d_in[0];
    const int*   ei  = (const int*)d_in[1];
    const float* eps = (const float*)d_in[2];
    const float* W1  = (const float*)d_in[3];
    const float* b1  = (const float*)d_in[4];
    const float* g1  = (const float*)d_in[5];
    const float* be1 = (const float*)d_in[6];
    const float* W2  = (const float*)d_in[7];
    const float* b2  = (const float*)d_in[8];
    const float* g2  = (const float*)d_in[9];
    const float* be2 = (const float*)d_in[10];

    int N = in_sizes[0] / D;       // 50000
    int E = in_sizes[1] / 2;       // 800000

    float* buf   = (float*)d_ws;                 // N*D floats: aggr, later z2
    float* stats = buf + (size_t)N * D;          // 1024 floats
    float* sum1 = stats +   0, *sq1 = stats + 128, *s1 = stats + 256, *t1 = stats + 384;
    float* sum2 = stats + 512, *sq2 = stats + 640, *s2 = stats + 768, *t2 = stats + 896;
    float* z1 = (float*)d_out;                   // z1 staged in d_out

    hipMemsetAsync(buf, 0, (size_t)N * D * sizeof(float), stream);
    hipMemsetAsync(stats, 0, 1024 * sizeof(float), stream);

    int total = E * 32;
    scatter_kernel<<<(total + 255) / 256, 256, 0, stream>>>(
        (const float4*)x, ei, buf, E, total);

    int gblocks = (N + 63) / 64;
    // layer 1: z1 = ((1+eps)x + aggr) @ W1 + b1 ; stats1
    gemm_bn_kernel<<<gblocks, 256, 0, stream>>>(
        x, buf, eps, nullptr, nullptr, W1, b1, z1, sum1, sq1, N, 0);
    bn_finalize_kernel<<<1, 128, 0, stream>>>(sum1, sq1, g1, be1, s1, t1, 1.0f / N);
    // layer 2: z2 = relu(bn1(z1)) @ W2 + b2 ; stats2  (z2 overwrites aggr buf)
    gemm_bn_kernel<<<gblocks, 256, 0, stream>>>(
        z1, nullptr, nullptr, s1, t1, W2, b2, buf, sum2, sq2, N, 1);
    bn_finalize_kernel<<<1, 128, 0, stream>>>(sum2, sq2, g2, be2, s2, t2, 1.0f / N);
    // out = relu(bn2(z2))
    bn_relu_kernel<<<(N * 32 + 255) / 256, 256, 0, stream>>>(
        (const float4*)buf, (float4*)d_out, s2, t2, N * 32);
}

// Round 2
// 517.591 us; speedup vs baseline: 3.0981x; 3.0981x over previous
//
#include <hip/hip_runtime.h>

#define D 128
#define D4 32       // float4 per row
#define D2 64       // float2 per row
#define ZSTRIDE 132 // padded LDS stride for z tile

// ---------------- CSR build: histogram of dst ----------------
__global__ __launch_bounds__(256) void hist_kernel(
    const int* __restrict__ ei, int* __restrict__ counts, int E)
{
    int e = blockIdx.x * 256 + threadIdx.x;
    if (e >= E) return;
    atomicAdd(&counts[ei[E + e]], 1);
}

// ---------------- CSR build: exclusive scan (single block) ----------------
__global__ __launch_bounds__(256) void scan_kernel(
    const int* __restrict__ counts, int* __restrict__ row_ptr,
    int* __restrict__ cursor, int N, int E)
{
    __shared__ int partial[256];
    int tid = threadIdx.x;
    int chunk = (N + 255) / 256;
    int start = tid * chunk;
    int end = start + chunk; if (end > N) end = N;

    int s = 0;
    for (int i = start; i < end; ++i) s += counts[i];
    partial[tid] = s;
    __syncthreads();
    if (tid == 0) {
        int run = 0;
        for (int i = 0; i < 256; ++i) { int t = partial[i]; partial[i] = run; run += t; }
    }
    __syncthreads();
    int run = partial[tid];
    for (int i = start; i < end; ++i) {
        row_ptr[i] = run;
        cursor[i] = run;
        run += counts[i];
    }
    if (tid == 0) row_ptr[N] = E;
}

// ---------------- CSR build: fill sorted src ----------------
__global__ __launch_bounds__(256) void fill_kernel(
    const int* __restrict__ ei, int* __restrict__ cursor,
    int* __restrict__ sorted_src, int E)
{
    int e = blockIdx.x * 256 + threadIdx.x;
    if (e >= E) return;
    int src = ei[e];
    int dst = ei[E + e];
    int pos = atomicAdd(&cursor[dst], 1);
    sorted_src[pos] = src;
}

// ---------------- gather: h0[n] = (1+eps)*x[n] + sum_{e in row n} x[src_e] ----
__global__ __launch_bounds__(256) void gather_kernel(
    const float2* __restrict__ x2, const int* __restrict__ row_ptr,
    const int* __restrict__ sorted_src, const float* __restrict__ epsp,
    float2* __restrict__ h0, int N)
{
    int gtid = blockIdx.x * 256 + threadIdx.x;
    int node = gtid >> 6;
    int lane = gtid & 63;
    if (node >= N) return;

    float epsv = 1.0f + __ldg(epsp);
    float2 xv = x2[(size_t)node * D2 + lane];
    float2 acc;
    acc.x = epsv * xv.x;
    acc.y = epsv * xv.y;

    int beg = row_ptr[node];
    int end = row_ptr[node + 1];
    int e = beg;
    for (; e + 1 < end; e += 2) {
        int s0 = sorted_src[e];
        int s1 = sorted_src[e + 1];
        float2 v0 = x2[(size_t)s0 * D2 + lane];
        float2 v1 = x2[(size_t)s1 * D2 + lane];
        acc.x += v0.x + v1.x;
        acc.y += v0.y + v1.y;
    }
    if (e < end) {
        int s0 = sorted_src[e];
        float2 v0 = x2[(size_t)s0 * D2 + lane];
        acc.x += v0.x;
        acc.y += v0.y;
    }
    h0[(size_t)node * D2 + lane] = acc;
}

// ---------------- fused GEMM + BN-stat accumulation ----------------
// mode 0: in = in0 (identity)
// mode 1: in = relu(in0*sc[k] + sh[k])
__global__ __launch_bounds__(256) void gemm_bn_kernel(
    const float* __restrict__ in0,
    const float* __restrict__ sc,
    const float* __restrict__ sh,
    const float* __restrict__ W,
    const float* __restrict__ bias,
    float* __restrict__ zout,
    float* __restrict__ stat_sum, float* __restrict__ stat_sq,
    int N, int mode)
{
    __shared__ float Wl[D * D];   // 64 KB
    int tid = threadIdx.x;

    float4* Wl4 = (float4*)Wl;
    const float4* W4 = (const float4*)W;
    #pragma unroll
    for (int i = 0; i < 16; ++i) Wl4[tid + i * 256] = W4[tid + i * 256];
    __syncthreads();

    int rloc = tid >> 2;
    int r = blockIdx.x * 64 + rloc;
    int cg = tid & 3;
    int c0 = cg * 32;

    float acc[32];
    #pragma unroll
    for (int j = 0; j < 32; ++j) acc[j] = bias[c0 + j];

    bool valid = (r < N);
    if (valid) {
        const float4* row0 = (const float4*)(in0 + (size_t)r * D);

        for (int kk = 0; kk < D; kk += 16) {
            float a[16];
            #pragma unroll
            for (int q = 0; q < 4; ++q) {
                float4 v = row0[(kk >> 2) + q];
                if (mode == 1) {
                    int c = kk + q * 4;
                    v.x = fmaxf(fmaf(v.x, __ldg(sc + c + 0), __ldg(sh + c + 0)), 0.f);
                    v.y = fmaxf(fmaf(v.y, __ldg(sc + c + 1), __ldg(sh + c + 1)), 0.f);
                    v.z = fmaxf(fmaf(v.z, __ldg(sc + c + 2), __ldg(sh + c + 2)), 0.f);
                    v.w = fmaxf(fmaf(v.w, __ldg(sc + c + 3), __ldg(sh + c + 3)), 0.f);
                }
                a[q * 4 + 0] = v.x; a[q * 4 + 1] = v.y;
                a[q * 4 + 2] = v.z; a[q * 4 + 3] = v.w;
            }
            #pragma unroll
            for (int k2 = 0; k2 < 16; ++k2) {
                float av = a[k2];
                const float4* wrow = Wl4 + (kk + k2) * D4 + cg * 8;
                #pragma unroll
                for (int j8 = 0; j8 < 8; ++j8) {
                    float4 w = wrow[j8];
                    acc[j8 * 4 + 0] = fmaf(av, w.x, acc[j8 * 4 + 0]);
                    acc[j8 * 4 + 1] = fmaf(av, w.y, acc[j8 * 4 + 1]);
                    acc[j8 * 4 + 2] = fmaf(av, w.z, acc[j8 * 4 + 2]);
                    acc[j8 * 4 + 3] = fmaf(av, w.w, acc[j8 * 4 + 3]);
                }
            }
        }
    }

    __syncthreads();
    float* zl = Wl;

    if (valid) {
        float4* zrow = (float4*)(zout + (size_t)r * D);
        #pragma unroll
        for (int j8 = 0; j8 < 8; ++j8) {
            float4 v = make_float4(acc[j8 * 4 + 0], acc[j8 * 4 + 1],
                                   acc[j8 * 4 + 2], acc[j8 * 4 + 3]);
            zrow[cg * 8 + j8] = v;
            *((float4*)&zl[rloc * ZSTRIDE + c0 + j8 * 4]) = v;
        }
    }
    __syncthreads();

    if (tid < D) {
        int rows = N - blockIdx.x * 64;
        if (rows > 64) rows = 64;
        float s = 0.f, q = 0.f;
        for (int rr = 0; rr < rows; ++rr) {
            float v = zl[rr * ZSTRIDE + tid];
            s += v;
            q = fmaf(v, v, q);
        }
        atomicAdd(&stat_sum[tid], s);
        atomicAdd(&stat_sq[tid], q);
    }
}

// ---------------- BN finalize ----------------
__global__ void bn_finalize_kernel(
    const float* __restrict__ stat_sum, const float* __restrict__ stat_sq,
    const float* __restrict__ gamma, const float* __restrict__ beta,
    float* __restrict__ s_out, float* __restrict__ t_out, float invN)
{
    int c = threadIdx.x;
    float mean = stat_sum[c] * invN;
    float var  = stat_sq[c] * invN - mean * mean;
    float s = gamma[c] * rsqrtf(var + 1e-5f);
    s_out[c] = s;
    t_out[c] = fmaf(-mean, s, beta[c]);
}

// ---------------- final BN + ReLU elementwise ----------------
__global__ __launch_bounds__(256) void bn_relu_kernel(
    const float4* __restrict__ z, float4* __restrict__ out,
    const float* __restrict__ s, const float* __restrict__ t, int total4)
{
    int i = blockIdx.x * 256 + threadIdx.x;
    if (i >= total4) return;
    float4 v = z[i];
    int c = (i & 31) * 4;
    float4 o;
    o.x = fmaxf(fmaf(v.x, s[c + 0], t[c + 0]), 0.f);
    o.y = fmaxf(fmaf(v.y, s[c + 1], t[c + 1]), 0.f);
    o.z = fmaxf(fmaf(v.z, s[c + 2], t[c + 2]), 0.f);
    o.w = fmaxf(fmaf(v.w, s[c + 3], t[c + 3]), 0.f);
    out[i] = o;
}

extern "C" void kernel_launch(void* const* d_in, const int* in_sizes, int n_in,
                              void* d_out, int out_size, void* d_ws, size_t ws_size,
                              hipStream_t stream)
{
    const float* x   = (const float*)d_in[0];
    const int*   ei  = (const int*)d_in[1];
    const float* eps = (const float*)d_in[2];
    const float* W1  = (const float*)d_in[3];
    const float* b1  = (const float*)d_in[4];
    const float* g1  = (const float*)d_in[5];
    const float* be1 = (const float*)d_in[6];
    const float* W2  = (const float*)d_in[7];
    const float* b2  = (const float*)d_in[8];
    const float* g2  = (const float*)d_in[9];
    const float* be2 = (const float*)d_in[10];

    int N = in_sizes[0] / D;       // 50000
    int E = in_sizes[1] / 2;       // 800000

    // workspace layout (floats/ints):
    float* h0    = (float*)d_ws;                      // N*D floats (reused as z2)
    float* stats = h0 + (size_t)N * D;                // 1024 floats
    int* counts  = (int*)(stats + 1024);              // N ints
    int* row_ptr = counts + N;                        // N+1 ints
    int* cursor  = row_ptr + N + 1;                   // N ints
    int* sorted  = cursor + N;                        // E ints

    float* sum1 = stats +   0, *sq1 = stats + 128, *s1 = stats + 256, *t1 = stats + 384;
    float* sum2 = stats + 512, *sq2 = stats + 640, *s2 = stats + 768, *t2 = stats + 896;
    float* z1 = (float*)d_out;

    hipMemsetAsync(stats, 0, 1024 * sizeof(float), stream);
    hipMemsetAsync(counts, 0, (size_t)N * sizeof(int), stream);

    int eblocks = (E + 255) / 256;
    hist_kernel<<<eblocks, 256, 0, stream>>>(ei, counts, E);
    scan_kernel<<<1, 256, 0, stream>>>(counts, row_ptr, cursor, N, E);
    fill_kernel<<<eblocks, 256, 0, stream>>>(ei, cursor, sorted, E);
    gather_kernel<<<(N * 64 + 255) / 256, 256, 0, stream>>>(
        (const float2*)x, row_ptr, sorted, eps, (float2*)h0, N);

    int gblocks = (N + 63) / 64;
    gemm_bn_kernel<<<gblocks, 256, 0, stream>>>(
        h0, nullptr, nullptr, W1, b1, z1, sum1, sq1, N, 0);
    bn_finalize_kernel<<<1, 128, 0, stream>>>(sum1, sq1, g1, be1, s1, t1, 1.0f / N);
    gemm_bn_kernel<<<gblocks, 256, 0, stream>>>(
        z1, s1, t1, W2, b2, h0, sum2, sq2, N, 1);
    bn_finalize_kernel<<<1, 128, 0, stream>>>(sum2, sq2, g2, be2, s2, t2, 1.0f / N);
    bn_relu_kernel<<<(N * 32 + 255) / 256, 256, 0, stream>>>(
        (const float4*)h0, (float4*)d_out, s2, t2, N * 32);
}

// Round 3
// 404.514 us; speedup vs baseline: 3.9641x; 1.2795x over previous
//
#include <hip/hip_runtime.h>

#define D 128
#define D4 32       // float4 per row
#define D2 64       // float2 per row
#define ZSTRIDE 132 // padded LDS stride for z tile
#define SCAN_CHUNK 1024

// ---------------- CSR build: histogram of dst ----------------
__global__ __launch_bounds__(256) void hist_kernel(
    const int* __restrict__ ei, int* __restrict__ counts, int E)
{
    int e = blockIdx.x * 256 + threadIdx.x;
    if (e >= E) return;
    atomicAdd(&counts[ei[E + e]], 1);
}

// ---------------- scan phase A: per-chunk partial sums ----------------
__global__ __launch_bounds__(256) void partial_sum_kernel(
    const int* __restrict__ counts, int* __restrict__ partials, int N)
{
    int tid = threadIdx.x, b = blockIdx.x;
    int base = b * SCAN_CHUNK + tid * 4;
    int t = 0;
    #pragma unroll
    for (int j = 0; j < 4; ++j)
        if (base + j < N) t += counts[base + j];
    int lane = tid & 63, wid = tid >> 6;
    #pragma unroll
    for (int off = 32; off; off >>= 1) t += __shfl_down(t, off, 64);
    __shared__ int ws[4];
    if (lane == 0) ws[wid] = t;
    __syncthreads();
    if (tid == 0) partials[b] = ws[0] + ws[1] + ws[2] + ws[3];
}

// ---------------- scan phase B: scan the partials (1 small block) --------
__global__ __launch_bounds__(256) void scan_partials_kernel(
    int* __restrict__ partials, int nchunks,
    int* __restrict__ row_ptr, int N, int E)
{
    __shared__ int sm[256];
    int tid = threadIdx.x;
    int v = (tid < nchunks) ? partials[tid] : 0;
    sm[tid] = v;
    __syncthreads();
    #pragma unroll
    for (int off = 1; off < 256; off <<= 1) {
        int u = (tid >= off) ? sm[tid - off] : 0;
        __syncthreads();
        sm[tid] += u;
        __syncthreads();
    }
    if (tid < nchunks) partials[tid] = sm[tid] - v;  // exclusive
    if (tid == 0) row_ptr[N] = E;
}

// ---------------- scan phase C: in-chunk exclusive scan ----------------
__global__ __launch_bounds__(256) void scan_chunk_kernel(
    const int* __restrict__ counts, const int* __restrict__ partials,
    int* __restrict__ row_ptr, int* __restrict__ cursor, int N)
{
    int tid = threadIdx.x, b = blockIdx.x;
    int base = b * SCAN_CHUNK + tid * 4;
    int c[4]; int t = 0;
    #pragma unroll
    for (int j = 0; j < 4; ++j) {
        c[j] = (base + j < N) ? counts[base + j] : 0;
        t += c[j];
    }
    int lane = tid & 63, wid = tid >> 6;
    int v = t;
    #pragma unroll
    for (int off = 1; off < 64; off <<= 1) {
        int u = __shfl_up(v, off, 64);
        if (lane >= off) v += u;
    }
    __shared__ int ws[4];
    if (lane == 63) ws[wid] = v;
    __syncthreads();
    int woff = 0;
    #pragma unroll
    for (int w = 0; w < 4; ++w) if (w < wid) woff += ws[w];
    int ex = partials[b] + woff + (v - t);
    #pragma unroll
    for (int j = 0; j < 4; ++j) {
        if (base + j < N) { row_ptr[base + j] = ex; cursor[base + j] = ex; }
        ex += c[j];
    }
}

// ---------------- CSR build: fill sorted src ----------------
__global__ __launch_bounds__(256) void fill_kernel(
    const int* __restrict__ ei, int* __restrict__ cursor,
    int* __restrict__ sorted_src, int E)
{
    int e = blockIdx.x * 256 + threadIdx.x;
    if (e >= E) return;
    int src = ei[e];
    int dst = ei[E + e];
    int pos = atomicAdd(&cursor[dst], 1);
    sorted_src[pos] = src;
}

// ---------------- gather: h0[n] = (1+eps)*x[n] + sum_{e in row n} x[src_e] ----
__global__ __launch_bounds__(256) void gather_kernel(
    const float2* __restrict__ x2, const int* __restrict__ row_ptr,
    const int* __restrict__ sorted_src, const float* __restrict__ epsp,
    float2* __restrict__ h0, int N)
{
    int gtid = blockIdx.x * 256 + threadIdx.x;
    int node = gtid >> 6;
    int lane = gtid & 63;
    if (node >= N) return;

    float epsv = 1.0f + __ldg(epsp);
    float2 xv = x2[(size_t)node * D2 + lane];
    float2 acc;
    acc.x = epsv * xv.x;
    acc.y = epsv * xv.y;

    int beg = row_ptr[node];
    int end = row_ptr[node + 1];
    int e = beg;
    for (; e + 1 < end; e += 2) {
        int s0 = sorted_src[e];
        int s1 = sorted_src[e + 1];
        float2 v0 = x2[(size_t)s0 * D2 + lane];
        float2 v1 = x2[(size_t)s1 * D2 + lane];
        acc.x += v0.x + v1.x;
        acc.y += v0.y + v1.y;
    }
    if (e < end) {
        int s0 = sorted_src[e];
        float2 v0 = x2[(size_t)s0 * D2 + lane];
        acc.x += v0.x;
        acc.y += v0.y;
    }
    h0[(size_t)node * D2 + lane] = acc;
}

// ---------------- fused GEMM + BN-stat accumulation ----------------
// mode 0: in = in0 (identity)
// mode 1: in = relu(in0*sc[k] + sh[k])
__global__ __launch_bounds__(256) void gemm_bn_kernel(
    const float* __restrict__ in0,
    const float* __restrict__ sc,
    const float* __restrict__ sh,
    const float* __restrict__ W,
    const float* __restrict__ bias,
    float* __restrict__ zout,
    float* __restrict__ stat_sum, float* __restrict__ stat_sq,
    int N, int mode)
{
    __shared__ float Wl[D * D];   // 64 KB
    int tid = threadIdx.x;

    float4* Wl4 = (float4*)Wl;
    const float4* W4 = (const float4*)W;
    #pragma unroll
    for (int i = 0; i < 16; ++i) Wl4[tid + i * 256] = W4[tid + i * 256];
    __syncthreads();

    int rloc = tid >> 2;
    int r = blockIdx.x * 64 + rloc;
    int cg = tid & 3;
    int c0 = cg * 32;

    float acc[32];
    #pragma unroll
    for (int j = 0; j < 32; ++j) acc[j] = bias[c0 + j];

    bool valid = (r < N);
    if (valid) {
        const float4* row0 = (const float4*)(in0 + (size_t)r * D);

        for (int kk = 0; kk < D; kk += 16) {
            float a[16];
            #pragma unroll
            for (int q = 0; q < 4; ++q) {
                float4 v = row0[(kk >> 2) + q];
                if (mode == 1) {
                    int c = kk + q * 4;
                    v.x = fmaxf(fmaf(v.x, __ldg(sc + c + 0), __ldg(sh + c + 0)), 0.f);
                    v.y = fmaxf(fmaf(v.y, __ldg(sc + c + 1), __ldg(sh + c + 1)), 0.f);
                    v.z = fmaxf(fmaf(v.z, __ldg(sc + c + 2), __ldg(sh + c + 2)), 0.f);
                    v.w = fmaxf(fmaf(v.w, __ldg(sc + c + 3), __ldg(sh + c + 3)), 0.f);
                }
                a[q * 4 + 0] = v.x; a[q * 4 + 1] = v.y;
                a[q * 4 + 2] = v.z; a[q * 4 + 3] = v.w;
            }
            #pragma unroll
            for (int k2 = 0; k2 < 16; ++k2) {
                float av = a[k2];
                const float4* wrow = Wl4 + (kk + k2) * D4 + cg * 8;
                #pragma unroll
                for (int j8 = 0; j8 < 8; ++j8) {
                    float4 w = wrow[j8];
                    acc[j8 * 4 + 0] = fmaf(av, w.x, acc[j8 * 4 + 0]);
                    acc[j8 * 4 + 1] = fmaf(av, w.y, acc[j8 * 4 + 1]);
                    acc[j8 * 4 + 2] = fmaf(av, w.z, acc[j8 * 4 + 2]);
                    acc[j8 * 4 + 3] = fmaf(av, w.w, acc[j8 * 4 + 3]);
                }
            }
        }
    }

    __syncthreads();
    float* zl = Wl;

    if (valid) {
        float4* zrow = (float4*)(zout + (size_t)r * D);
        #pragma unroll
        for (int j8 = 0; j8 < 8; ++j8) {
            float4 v = make_float4(acc[j8 * 4 + 0], acc[j8 * 4 + 1],
                                   acc[j8 * 4 + 2], acc[j8 * 4 + 3]);
            zrow[cg * 8 + j8] = v;
            *((float4*)&zl[rloc * ZSTRIDE + c0 + j8 * 4]) = v;
        }
    }
    __syncthreads();

    if (tid < D) {
        int rows = N - blockIdx.x * 64;
        if (rows > 64) rows = 64;
        float s = 0.f, q = 0.f;
        for (int rr = 0; rr < rows; ++rr) {
            float v = zl[rr * ZSTRIDE + tid];
            s += v;
            q = fmaf(v, v, q);
        }
        atomicAdd(&stat_sum[tid], s);
        atomicAdd(&stat_sq[tid], q);
    }
}

// ---------------- BN finalize ----------------
__global__ void bn_finalize_kernel(
    const float* __restrict__ stat_sum, const float* __restrict__ stat_sq,
    const float* __restrict__ gamma, const float* __restrict__ beta,
    float* __restrict__ s_out, float* __restrict__ t_out, float invN)
{
    int c = threadIdx.x;
    float mean = stat_sum[c] * invN;
    float var  = stat_sq[c] * invN - mean * mean;
    float s = gamma[c] * rsqrtf(var + 1e-5f);
    s_out[c] = s;
    t_out[c] = fmaf(-mean, s, beta[c]);
}

// ---------------- final BN + ReLU elementwise ----------------
__global__ __launch_bounds__(256) void bn_relu_kernel(
    const float4* __restrict__ z, float4* __restrict__ out,
    const float* __restrict__ s, const float* __restrict__ t, int total4)
{
    int i = blockIdx.x * 256 + threadIdx.x;
    if (i >= total4) return;
    float4 v = z[i];
    int c = (i & 31) * 4;
    float4 o;
    o.x = fmaxf(fmaf(v.x, s[c + 0], t[c + 0]), 0.f);
    o.y = fmaxf(fmaf(v.y, s[c + 1], t[c + 1]), 0.f);
    o.z = fmaxf(fmaf(v.z, s[c + 2], t[c + 2]), 0.f);
    o.w = fmaxf(fmaf(v.w, s[c + 3], t[c + 3]), 0.f);
    out[i] = o;
}

extern "C" void kernel_launch(void* const* d_in, const int* in_sizes, int n_in,
                              void* d_out, int out_size, void* d_ws, size_t ws_size,
                              hipStream_t stream)
{
    const float* x   = (const float*)d_in[0];
    const int*   ei  = (const int*)d_in[1];
    const float* eps = (const float*)d_in[2];
    const float* W1  = (const float*)d_in[3];
    const float* b1  = (const float*)d_in[4];
    const float* g1  = (const float*)d_in[5];
    const float* be1 = (const float*)d_in[6];
    const float* W2  = (const float*)d_in[7];
    const float* b2  = (const float*)d_in[8];
    const float* g2  = (const float*)d_in[9];
    const float* be2 = (const float*)d_in[10];

    int N = in_sizes[0] / D;       // 50000
    int E = in_sizes[1] / 2;       // 800000

    // workspace layout:
    float* h0    = (float*)d_ws;                      // N*D floats (reused as z2)
    float* stats = h0 + (size_t)N * D;                // 1024 floats
    int* counts  = (int*)(stats + 1024);              // N ints
    int* row_ptr = counts + N;                        // N+1 ints
    int* cursor  = row_ptr + N + 1;                   // N ints
    int* partials= cursor + N;                        // 256 ints
    int* sorted  = partials + 256;                    // E ints

    float* sum1 = stats +   0, *sq1 = stats + 128, *s1 = stats + 256, *t1 = stats + 384;
    float* sum2 = stats + 512, *sq2 = stats + 640, *s2 = stats + 768, *t2 = stats + 896;
    float* z1 = (float*)d_out;

    hipMemsetAsync(stats, 0, 1024 * sizeof(float), stream);
    hipMemsetAsync(counts, 0, (size_t)N * sizeof(int), stream);

    int eblocks = (E + 255) / 256;
    int nchunks = (N + SCAN_CHUNK - 1) / SCAN_CHUNK;
    hist_kernel<<<eblocks, 256, 0, stream>>>(ei, counts, E);
    partial_sum_kernel<<<nchunks, 256, 0, stream>>>(counts, partials, N);
    scan_partials_kernel<<<1, 256, 0, stream>>>(partials, nchunks, row_ptr, N, E);
    scan_chunk_kernel<<<nchunks, 256, 0, stream>>>(counts, partials, row_ptr, cursor, N);
    fill_kernel<<<eblocks, 256, 0, stream>>>(ei, cursor, sorted, E);
    gather_kernel<<<(N * 64 + 255) / 256, 256, 0, stream>>>(
        (const float2*)x, row_ptr, sorted, eps, (float2*)h0, N);

    int gblocks = (N + 63) / 64;
    gemm_bn_kernel<<<gblocks, 256, 0, stream>>>(
        h0, nullptr, nullptr, W1, b1, z1, sum1, sq1, N, 0);
    bn_finalize_kernel<<<1, 128, 0, stream>>>(sum1, sq1, g1, be1, s1, t1, 1.0f / N);
    gemm_bn_kernel<<<gblocks, 256, 0, stream>>>(
        z1, s1, t1, W2, b2, h0, sum2, sq2, N, 1);
    bn_finalize_kernel<<<1, 128, 0, stream>>>(sum2, sq2, g2, be2, s2, t2, 1.0f / N);
    bn_relu_kernel<<<(N * 32 + 255) / 256, 256, 0, stream>>>(
        (const float4*)h0, (float4*)d_out, s2, t2, N * 32);
}

// Round 4
// 329.555 us; speedup vs baseline: 4.8658x; 1.2275x over previous
//
#include <hip/hip_runtime.h>

#define D 128
#define D2 64       // float2 per row
#define SCAN_CHUNK 1024

typedef __attribute__((ext_vector_type(8))) short short8;
typedef __attribute__((ext_vector_type(4))) float f32x4;

static __device__ __forceinline__ unsigned short f2bf(float f) {
    union { float f; unsigned u; } v; v.f = f;
    unsigned r = v.u + 0x7FFF + ((v.u >> 16) & 1);   // RNE
    return (unsigned short)(r >> 16);
}

// ---------------- CSR build: histogram of dst ----------------
__global__ __launch_bounds__(256) void hist_kernel(
    const int* __restrict__ ei, int* __restrict__ counts, int E)
{
    int e = blockIdx.x * 256 + threadIdx.x;
    if (e >= E) return;
    atomicAdd(&counts[ei[E + e]], 1);
}

// ---------------- scan phase A: per-chunk partial sums ----------------
__global__ __launch_bounds__(256) void partial_sum_kernel(
    const int* __restrict__ counts, int* __restrict__ partials, int N)
{
    int tid = threadIdx.x, b = blockIdx.x;
    int base = b * SCAN_CHUNK + tid * 4;
    int t = 0;
    #pragma unroll
    for (int j = 0; j < 4; ++j)
        if (base + j < N) t += counts[base + j];
    int lane = tid & 63, wid = tid >> 6;
    #pragma unroll
    for (int off = 32; off; off >>= 1) t += __shfl_down(t, off, 64);
    __shared__ int ws[4];
    if (lane == 0) ws[wid] = t;
    __syncthreads();
    if (tid == 0) partials[b] = ws[0] + ws[1] + ws[2] + ws[3];
}

// ---------------- scan phase B: scan the partials (1 small block) --------
__global__ __launch_bounds__(256) void scan_partials_kernel(
    int* __restrict__ partials, int nchunks,
    int* __restrict__ row_ptr, int N, int E)
{
    __shared__ int sm[256];
    int tid = threadIdx.x;
    int v = (tid < nchunks) ? partials[tid] : 0;
    sm[tid] = v;
    __syncthreads();
    #pragma unroll
    for (int off = 1; off < 256; off <<= 1) {
        int u = (tid >= off) ? sm[tid - off] : 0;
        __syncthreads();
        sm[tid] += u;
        __syncthreads();
    }
    if (tid < nchunks) partials[tid] = sm[tid] - v;  // exclusive
    if (tid == 0) row_ptr[N] = E;
}

// ---------------- scan phase C: in-chunk exclusive scan ----------------
__global__ __launch_bounds__(256) void scan_chunk_kernel(
    const int* __restrict__ counts, const int* __restrict__ partials,
    int* __restrict__ row_ptr, int* __restrict__ cursor, int N)
{
    int tid = threadIdx.x, b = blockIdx.x;
    int base = b * SCAN_CHUNK + tid * 4;
    int c[4]; int t = 0;
    #pragma unroll
    for (int j = 0; j < 4; ++j) {
        c[j] = (base + j < N) ? counts[base + j] : 0;
        t += c[j];
    }
    int lane = tid & 63, wid = tid >> 6;
    int v = t;
    #pragma unroll
    for (int off = 1; off < 64; off <<= 1) {
        int u = __shfl_up(v, off, 64);
        if (lane >= off) v += u;
    }
    __shared__ int ws[4];
    if (lane == 63) ws[wid] = v;
    __syncthreads();
    int woff = 0;
    #pragma unroll
    for (int w = 0; w < 4; ++w) if (w < wid) woff += ws[w];
    int ex = partials[b] + woff + (v - t);
    #pragma unroll
    for (int j = 0; j < 4; ++j) {
        if (base + j < N) { row_ptr[base + j] = ex; cursor[base + j] = ex; }
        ex += c[j];
    }
}

// ---------------- CSR build: fill sorted src ----------------
__global__ __launch_bounds__(256) void fill_kernel(
    const int* __restrict__ ei, int* __restrict__ cursor,
    int* __restrict__ sorted_src, int E)
{
    int e = blockIdx.x * 256 + threadIdx.x;
    if (e >= E) return;
    int src = ei[e];
    int dst = ei[E + e];
    int pos = atomicAdd(&cursor[dst], 1);
    sorted_src[pos] = src;
}

// ---------------- gather: h0[n] = (1+eps)*x[n] + sum_{e in row n} x[src_e] ----
__global__ __launch_bounds__(256) void gather_kernel(
    const float2* __restrict__ x2, const int* __restrict__ row_ptr,
    const int* __restrict__ sorted_src, const float* __restrict__ epsp,
    float2* __restrict__ h0, int N)
{
    int gtid = blockIdx.x * 256 + threadIdx.x;
    int node = gtid >> 6;
    int lane = gtid & 63;
    if (node >= N) return;

    float epsv = 1.0f + __ldg(epsp);
    float2 xv = x2[(size_t)node * D2 + lane];
    float2 acc;
    acc.x = epsv * xv.x;
    acc.y = epsv * xv.y;

    int beg = row_ptr[node];
    int end = row_ptr[node + 1];
    int e = beg;
    for (; e + 1 < end; e += 2) {
        int s0 = sorted_src[e];
        int s1 = sorted_src[e + 1];
        float2 v0 = x2[(size_t)s0 * D2 + lane];
        float2 v1 = x2[(size_t)s1 * D2 + lane];
        acc.x += v0.x + v1.x;
        acc.y += v0.y + v1.y;
    }
    if (e < end) {
        int s0 = sorted_src[e];
        float2 v0 = x2[(size_t)s0 * D2 + lane];
        acc.x += v0.x;
        acc.y += v0.y;
    }
    h0[(size_t)node * D2 + lane] = acc;
}

// ---------------- W prep: fp32 [k][n] -> bf16 fragment-ordered ----------------
// Wf[((kk*8+ct)*64 + lane)*8 + j] = bf16(W[(kk*32 + (lane>>4)*8 + j)*128 + ct*16 + (lane&15)])
__global__ __launch_bounds__(256) void wprep_kernel(
    const float* __restrict__ W1, const float* __restrict__ W2,
    unsigned short* __restrict__ Wf1, unsigned short* __restrict__ Wf2)
{
    int idx = blockIdx.x * 256 + threadIdx.x;   // 0..32767
    const float* W = (idx < 16384) ? W1 : W2;
    unsigned short* Wf = (idx < 16384) ? Wf1 : Wf2;
    int e = idx & 16383;
    int j = e & 7, lane = (e >> 3) & 63, ckk = e >> 9;
    int ct = ckk & 7, kk = ckk >> 3;
    int k = kk * 32 + (lane >> 4) * 8 + j;
    int n = ct * 16 + (lane & 15);
    Wf[e] = f2bf(W[k * 128 + n]);
}

// ---------------- MFMA GEMM + BN-stat accumulation ----------------
// mode 0: a = in0 ; mode 1: a = relu(in0*sc[k] + sh[k])
// z = a @ W + bias ; per-column sum/sumsq accumulated into stat_sum/stat_sq.
__global__ __launch_bounds__(256) void gemm_bn_mfma_kernel(
    const float* __restrict__ in0,
    const float* __restrict__ sc, const float* __restrict__ sh,
    const unsigned short* __restrict__ Wf, const float* __restrict__ bias,
    float* __restrict__ zout,
    float* __restrict__ stat_sum, float* __restrict__ stat_sq,
    int N, int mode)
{
    __shared__ unsigned short Wl[16384];   // 32 KB, fragment-ordered
    __shared__ float part[1024];           // [0..511]=sum partials, [512..1023]=sq

    int tid = threadIdx.x;

    // stage W fragments (conflict-free contiguous copy)
    {
        float4* dst = (float4*)Wl;
        const float4* srcp = (const float4*)Wf;
        #pragma unroll
        for (int i = 0; i < 8; ++i) dst[tid + i * 256] = srcp[tid + i * 256];
    }
    __syncthreads();

    int w = tid >> 6, lane = tid & 63, q = lane >> 4, n16 = lane & 15;
    int rowb = blockIdx.x * 64 + w * 16;

    // A-load row for this lane (clamped; invalid rows produce garbage that
    // only lands in invalid output rows, which are masked below)
    int m = rowb + n16;
    int mc = (m < N) ? m : (N - 1);
    const float* arow = in0 + (size_t)mc * D;

    f32x4 acc[8];
    #pragma unroll
    for (int ct = 0; ct < 8; ++ct) acc[ct] = (f32x4){0.f, 0.f, 0.f, 0.f};

    #pragma unroll
    for (int kk = 0; kk < 4; ++kk) {
        int c = kk * 32 + q * 8;
        float4 a0 = *(const float4*)(arow + c);
        float4 a1 = *(const float4*)(arow + c + 4);
        if (mode == 1) {
            float4 s0 = *(const float4*)(sc + c), s1 = *(const float4*)(sc + c + 4);
            float4 t0 = *(const float4*)(sh + c), t1 = *(const float4*)(sh + c + 4);
            a0.x = fmaxf(fmaf(a0.x, s0.x, t0.x), 0.f);
            a0.y = fmaxf(fmaf(a0.y, s0.y, t0.y), 0.f);
            a0.z = fmaxf(fmaf(a0.z, s0.z, t0.z), 0.f);
            a0.w = fmaxf(fmaf(a0.w, s0.w, t0.w), 0.f);
            a1.x = fmaxf(fmaf(a1.x, s1.x, t1.x), 0.f);
            a1.y = fmaxf(fmaf(a1.y, s1.y, t1.y), 0.f);
            a1.z = fmaxf(fmaf(a1.z, s1.z, t1.z), 0.f);
            a1.w = fmaxf(fmaf(a1.w, s1.w, t1.w), 0.f);
        }
        short8 af;
        af[0] = (short)f2bf(a0.x); af[1] = (short)f2bf(a0.y);
        af[2] = (short)f2bf(a0.z); af[3] = (short)f2bf(a0.w);
        af[4] = (short)f2bf(a1.x); af[5] = (short)f2bf(a1.y);
        af[6] = (short)f2bf(a1.z); af[7] = (short)f2bf(a1.w);

        #pragma unroll
        for (int ct = 0; ct < 8; ++ct) {
            short8 bf = *(const short8*)&Wl[(((kk * 8 + ct) * 64) + lane) * 8];
            acc[ct] = __builtin_amdgcn_mfma_f32_16x16x32_bf16(af, bf, acc[ct], 0, 0, 0);
        }
    }

    // epilogue: bias add, store, per-column stats
    #pragma unroll
    for (int ct = 0; ct < 8; ++ct) {
        int col = ct * 16 + n16;
        float bv = __ldg(bias + col);
        float s = 0.f, qs = 0.f;
        #pragma unroll
        for (int reg = 0; reg < 4; ++reg) {
            int row = rowb + q * 4 + reg;
            float v = acc[ct][reg] + bv;
            if (row < N) {
                zout[(size_t)row * D + col] = v;
                s += v;
                qs = fmaf(v, v, qs);
            }
        }
        s  += __shfl_xor(s, 16, 64);
        s  += __shfl_xor(s, 32, 64);
        qs += __shfl_xor(qs, 16, 64);
        qs += __shfl_xor(qs, 32, 64);
        if (lane < 16) {
            part[w * 128 + col] = s;            // col == ct*16 + lane here
            part[512 + w * 128 + col] = qs;
        }
    }
    __syncthreads();

    if (tid < 128) {
        float s  = part[tid] + part[128 + tid] + part[256 + tid] + part[384 + tid];
        float qq = part[512 + tid] + part[640 + tid] + part[768 + tid] + part[896 + tid];
        atomicAdd(&stat_sum[tid], s);
        atomicAdd(&stat_sq[tid], qq);
    }
}

// ---------------- BN finalize ----------------
__global__ void bn_finalize_kernel(
    const float* __restrict__ stat_sum, const float* __restrict__ stat_sq,
    const float* __restrict__ gamma, const float* __restrict__ beta,
    float* __restrict__ s_out, float* __restrict__ t_out, float invN)
{
    int c = threadIdx.x;
    float mean = stat_sum[c] * invN;
    float var  = stat_sq[c] * invN - mean * mean;
    float s = gamma[c] * rsqrtf(var + 1e-5f);
    s_out[c] = s;
    t_out[c] = fmaf(-mean, s, beta[c]);
}

// ---------------- final BN + ReLU elementwise ----------------
__global__ __launch_bounds__(256) void bn_relu_kernel(
    const float4* __restrict__ z, float4* __restrict__ out,
    const float* __restrict__ s, const float* __restrict__ t, int total4)
{
    int i = blockIdx.x * 256 + threadIdx.x;
    if (i >= total4) return;
    float4 v = z[i];
    int c = (i & 31) * 4;
    float4 o;
    o.x = fmaxf(fmaf(v.x, s[c + 0], t[c + 0]), 0.f);
    o.y = fmaxf(fmaf(v.y, s[c + 1], t[c + 1]), 0.f);
    o.z = fmaxf(fmaf(v.z, s[c + 2], t[c + 2]), 0.f);
    o.w = fmaxf(fmaf(v.w, s[c + 3], t[c + 3]), 0.f);
    out[i] = o;
}

extern "C" void kernel_launch(void* const* d_in, const int* in_sizes, int n_in,
                              void* d_out, int out_size, void* d_ws, size_t ws_size,
                              hipStream_t stream)
{
    const float* x   = (const float*)d_in[0];
    const int*   ei  = (const int*)d_in[1];
    const float* eps = (const float*)d_in[2];
    const float* W1  = (const float*)d_in[3];
    const float* b1  = (const float*)d_in[4];
    const float* g1  = (const float*)d_in[5];
    const float* be1 = (const float*)d_in[6];
    const float* W2  = (const float*)d_in[7];
    const float* b2  = (const float*)d_in[8];
    const float* g2  = (const float*)d_in[9];
    const float* be2 = (const float*)d_in[10];

    int N = in_sizes[0] / D;       // 50000
    int E = in_sizes[1] / 2;       // 800000

    // workspace layout:
    float* h0    = (float*)d_ws;                      // N*D floats (reused as z2)
    float* stats = h0 + (size_t)N * D;                // 1024 floats
    int* counts  = (int*)(stats + 1024);              // N ints
    int* row_ptr = counts + N;                        // N+1 ints
    int* cursor  = row_ptr + N + 1;                   // N ints
    int* partials= cursor + N;                        // 256 ints
    int* sorted  = partials + 256;                    // E ints
    unsigned short* Wf1 = (unsigned short*)(sorted + E);  // 16384 ushort
    unsigned short* Wf2 = Wf1 + 16384;                    // 16384 ushort

    float* sum1 = stats +   0, *sq1 = stats + 128, *s1 = stats + 256, *t1 = stats + 384;
    float* sum2 = stats + 512, *sq2 = stats + 640, *s2 = stats + 768, *t2 = stats + 896;
    float* z1 = (float*)d_out;

    hipMemsetAsync(stats, 0, 1024 * sizeof(float), stream);
    hipMemsetAsync(counts, 0, (size_t)N * sizeof(int), stream);

    int eblocks = (E + 255) / 256;
    int nchunks = (N + SCAN_CHUNK - 1) / SCAN_CHUNK;
    wprep_kernel<<<128, 256, 0, stream>>>(W1, W2, Wf1, Wf2);
    hist_kernel<<<eblocks, 256, 0, stream>>>(ei, counts, E);
    partial_sum_kernel<<<nchunks, 256, 0, stream>>>(counts, partials, N);
    scan_partials_kernel<<<1, 256, 0, stream>>>(partials, nchunks, row_ptr, N, E);
    scan_chunk_kernel<<<nchunks, 256, 0, stream>>>(counts, partials, row_ptr, cursor, N);
    fill_kernel<<<eblocks, 256, 0, stream>>>(ei, cursor, sorted, E);
    gather_kernel<<<(N * 64 + 255) / 256, 256, 0, stream>>>(
        (const float2*)x, row_ptr, sorted, eps, (float2*)h0, N);

    int gblocks = (N + 63) / 64;
    gemm_bn_mfma_kernel<<<gblocks, 256, 0, stream>>>(
        h0, nullptr, nullptr, Wf1, b1, z1, sum1, sq1, N, 0);
    bn_finalize_kernel<<<1, 128, 0, stream>>>(sum1, sq1, g1, be1, s1, t1, 1.0f / N);
    gemm_bn_mfma_kernel<<<gblocks, 256, 0, stream>>>(
        z1, s1, t1, Wf2, b2, h0, sum2, sq2, N, 1);
    bn_finalize_kernel<<<1, 128, 0, stream>>>(sum2, sq2, g2, be2, s2, t2, 1.0f / N);
    bn_relu_kernel<<<(N * 32 + 255) / 256, 256, 0, stream>>>(
        (const float4*)h0, (float4*)d_out, s2, t2, N * 32);
}

// Round 5
// 309.604 us; speedup vs baseline: 5.1793x; 1.0644x over previous
//
#include <hip/hip_runtime.h>

#define D 128
#define SCAN_CHUNK 1024

typedef __attribute__((ext_vector_type(8))) short short8;
typedef __attribute__((ext_vector_type(4))) float f32x4;

static __device__ __forceinline__ unsigned short f2bf(float f) {
    union { float f; unsigned u; } v; v.f = f;
    unsigned r = v.u + 0x7FFF + ((v.u >> 16) & 1);   // RNE
    return (unsigned short)(r >> 16);
}

static __device__ __forceinline__ float2 bfpair2f(unsigned p) {
    union { unsigned u; float f; } a, b;
    a.u = (p & 0xFFFFu) << 16;
    b.u = p & 0xFFFF0000u;
    return make_float2(a.f, b.f);
}

// ---------------- x -> bf16 row-major ----------------
__global__ __launch_bounds__(256) void xprep_kernel(
    const float4* __restrict__ x4, uint2* __restrict__ xh, int total)
{
    int i = blockIdx.x * 256 + threadIdx.x;
    if (i >= total) return;
    float4 v = x4[i];
    uint2 o;
    o.x = (unsigned)f2bf(v.x) | ((unsigned)f2bf(v.y) << 16);
    o.y = (unsigned)f2bf(v.z) | ((unsigned)f2bf(v.w) << 16);
    xh[i] = o;
}

// ---------------- CSR build: histogram of dst ----------------
__global__ __launch_bounds__(256) void hist_kernel(
    const int* __restrict__ ei, int* __restrict__ counts, int E)
{
    int e = blockIdx.x * 256 + threadIdx.x;
    if (e >= E) return;
    atomicAdd(&counts[ei[E + e]], 1);
}

// ---------------- scan phase A ----------------
__global__ __launch_bounds__(256) void partial_sum_kernel(
    const int* __restrict__ counts, int* __restrict__ partials, int N)
{
    int tid = threadIdx.x, b = blockIdx.x;
    int base = b * SCAN_CHUNK + tid * 4;
    int t = 0;
    #pragma unroll
    for (int j = 0; j < 4; ++j)
        if (base + j < N) t += counts[base + j];
    int lane = tid & 63, wid = tid >> 6;
    #pragma unroll
    for (int off = 32; off; off >>= 1) t += __shfl_down(t, off, 64);
    __shared__ int ws[4];
    if (lane == 0) ws[wid] = t;
    __syncthreads();
    if (tid == 0) partials[b] = ws[0] + ws[1] + ws[2] + ws[3];
}

// ---------------- scan phase B ----------------
__global__ __launch_bounds__(256) void scan_partials_kernel(
    int* __restrict__ partials, int nchunks,
    int* __restrict__ row_ptr, int N, int E)
{
    __shared__ int sm[256];
    int tid = threadIdx.x;
    int v = (tid < nchunks) ? partials[tid] : 0;
    sm[tid] = v;
    __syncthreads();
    #pragma unroll
    for (int off = 1; off < 256; off <<= 1) {
        int u = (tid >= off) ? sm[tid - off] : 0;
        __syncthreads();
        sm[tid] += u;
        __syncthreads();
    }
    if (tid < nchunks) partials[tid] = sm[tid] - v;  // exclusive
    if (tid == 0) row_ptr[N] = E;
}

// ---------------- scan phase C ----------------
__global__ __launch_bounds__(256) void scan_chunk_kernel(
    const int* __restrict__ counts, const int* __restrict__ partials,
    int* __restrict__ row_ptr, int* __restrict__ cursor, int N)
{
    int tid = threadIdx.x, b = blockIdx.x;
    int base = b * SCAN_CHUNK + tid * 4;
    int c[4]; int t = 0;
    #pragma unroll
    for (int j = 0; j < 4; ++j) {
        c[j] = (base + j < N) ? counts[base + j] : 0;
        t += c[j];
    }
    int lane = tid & 63, wid = tid >> 6;
    int v = t;
    #pragma unroll
    for (int off = 1; off < 64; off <<= 1) {
        int u = __shfl_up(v, off, 64);
        if (lane >= off) v += u;
    }
    __shared__ int ws[4];
    if (lane == 63) ws[wid] = v;
    __syncthreads();
    int woff = 0;
    #pragma unroll
    for (int w = 0; w < 4; ++w) if (w < wid) woff += ws[w];
    int ex = partials[b] + woff + (v - t);
    #pragma unroll
    for (int j = 0; j < 4; ++j) {
        if (base + j < N) { row_ptr[base + j] = ex; cursor[base + j] = ex; }
        ex += c[j];
    }
}

// ---------------- CSR build: fill sorted src ----------------
__global__ __launch_bounds__(256) void fill_kernel(
    const int* __restrict__ ei, int* __restrict__ cursor,
    int* __restrict__ sorted_src, int E)
{
    int e = blockIdx.x * 256 + threadIdx.x;
    if (e >= E) return;
    int src = ei[e];
    int dst = ei[E + e];
    int pos = atomicAdd(&cursor[dst], 1);
    sorted_src[pos] = src;
}

// -------- gather (bf16): h0[n] = bf16((1+eps)*x[n] + sum x[src]) --------
__global__ __launch_bounds__(256) void gather_kernel(
    const unsigned* __restrict__ xh, const int* __restrict__ row_ptr,
    const int* __restrict__ sorted_src, const float* __restrict__ epsp,
    unsigned* __restrict__ h0, int N)
{
    int gtid = blockIdx.x * 256 + threadIdx.x;
    int node = gtid >> 6;
    int lane = gtid & 63;
    if (node >= N) return;

    float epsv = 1.0f + __ldg(epsp);
    float2 xv = bfpair2f(xh[(size_t)node * 64 + lane]);
    float2 acc = make_float2(epsv * xv.x, epsv * xv.y);

    int beg = row_ptr[node];
    int end = row_ptr[node + 1];
    int e = beg;
    for (; e + 3 < end; e += 4) {
        int s0 = sorted_src[e],     s1 = sorted_src[e + 1];
        int s2 = sorted_src[e + 2], s3 = sorted_src[e + 3];
        unsigned p0 = xh[(size_t)s0 * 64 + lane];
        unsigned p1 = xh[(size_t)s1 * 64 + lane];
        unsigned p2 = xh[(size_t)s2 * 64 + lane];
        unsigned p3 = xh[(size_t)s3 * 64 + lane];
        float2 v0 = bfpair2f(p0), v1 = bfpair2f(p1);
        float2 v2 = bfpair2f(p2), v3 = bfpair2f(p3);
        acc.x += (v0.x + v1.x) + (v2.x + v3.x);
        acc.y += (v0.y + v1.y) + (v2.y + v3.y);
    }
    for (; e < end; ++e) {
        float2 v0 = bfpair2f(xh[(size_t)sorted_src[e] * 64 + lane]);
        acc.x += v0.x;
        acc.y += v0.y;
    }
    h0[(size_t)node * 64 + lane] =
        (unsigned)f2bf(acc.x) | ((unsigned)f2bf(acc.y) << 16);
}

// ---------------- W prep: fp32 [k][n] -> bf16 fragment-ordered ----------------
__global__ __launch_bounds__(256) void wprep_kernel(
    const float* __restrict__ W1, const float* __restrict__ W2,
    unsigned short* __restrict__ Wf1, unsigned short* __restrict__ Wf2)
{
    int idx = blockIdx.x * 256 + threadIdx.x;   // 0..32767
    const float* W = (idx < 16384) ? W1 : W2;
    unsigned short* Wf = (idx < 16384) ? Wf1 : Wf2;
    int e = idx & 16383;
    int j = e & 7, lane = (e >> 3) & 63, ckk = e >> 9;
    int ct = ckk & 7, kk = ckk >> 3;
    int k = kk * 32 + (lane >> 4) * 8 + j;
    int n = ct * 16 + (lane & 15);
    Wf[e] = f2bf(W[k * 128 + n]);
}

// ---------------- MFMA GEMM + BN-stat accumulation ----------------
// mode 0: A = a_bf (bf16 row-major, direct fragment load)
// mode 1: A = bf16(relu(a_f32*sc[k] + sh[k]))
__global__ __launch_bounds__(256) void gemm_bn_mfma_kernel(
    const unsigned short* __restrict__ a_bf,
    const float* __restrict__ a_f32,
    const float* __restrict__ sc, const float* __restrict__ sh,
    const unsigned short* __restrict__ Wf, const float* __restrict__ bias,
    float* __restrict__ zout,
    float* __restrict__ stat_sum, float* __restrict__ stat_sq,
    int N, int mode)
{
    __shared__ unsigned short Wl[16384];   // 32 KB, fragment-ordered
    __shared__ float part[1024];

    int tid = threadIdx.x;
    {
        float4* dst = (float4*)Wl;
        const float4* srcp = (const float4*)Wf;
        #pragma unroll
        for (int i = 0; i < 8; ++i) dst[tid + i * 256] = srcp[tid + i * 256];
    }
    __syncthreads();

    int w = tid >> 6, lane = tid & 63, q = lane >> 4, n16 = lane & 15;
    int rowb = blockIdx.x * 64 + w * 16;
    int m = rowb + n16;
    int mc = (m < N) ? m : (N - 1);

    f32x4 acc[8];
    #pragma unroll
    for (int ct = 0; ct < 8; ++ct) acc[ct] = (f32x4){0.f, 0.f, 0.f, 0.f};

    if (mode == 0) {
        const unsigned short* arow = a_bf + (size_t)mc * D;
        #pragma unroll
        for (int kk = 0; kk < 4; ++kk) {
            short8 af = *(const short8*)(arow + kk * 32 + q * 8);
            #pragma unroll
            for (int ct = 0; ct < 8; ++ct) {
                short8 bf = *(const short8*)&Wl[(((kk * 8 + ct) * 64) + lane) * 8];
                acc[ct] = __builtin_amdgcn_mfma_f32_16x16x32_bf16(af, bf, acc[ct], 0, 0, 0);
            }
        }
    } else {
        const float* arow = a_f32 + (size_t)mc * D;
        #pragma unroll
        for (int kk = 0; kk < 4; ++kk) {
            int c = kk * 32 + q * 8;
            float4 a0 = *(const float4*)(arow + c);
            float4 a1 = *(const float4*)(arow + c + 4);
            float4 s0 = *(const float4*)(sc + c), s1 = *(const float4*)(sc + c + 4);
            float4 t0 = *(const float4*)(sh + c), t1 = *(const float4*)(sh + c + 4);
            a0.x = fmaxf(fmaf(a0.x, s0.x, t0.x), 0.f);
            a0.y = fmaxf(fmaf(a0.y, s0.y, t0.y), 0.f);
            a0.z = fmaxf(fmaf(a0.z, s0.z, t0.z), 0.f);
            a0.w = fmaxf(fmaf(a0.w, s0.w, t0.w), 0.f);
            a1.x = fmaxf(fmaf(a1.x, s1.x, t1.x), 0.f);
            a1.y = fmaxf(fmaf(a1.y, s1.y, t1.y), 0.f);
            a1.z = fmaxf(fmaf(a1.z, s1.z, t1.z), 0.f);
            a1.w = fmaxf(fmaf(a1.w, s1.w, t1.w), 0.f);
            short8 af;
            af[0] = (short)f2bf(a0.x); af[1] = (short)f2bf(a0.y);
            af[2] = (short)f2bf(a0.z); af[3] = (short)f2bf(a0.w);
            af[4] = (short)f2bf(a1.x); af[5] = (short)f2bf(a1.y);
            af[6] = (short)f2bf(a1.z); af[7] = (short)f2bf(a1.w);
            #pragma unroll
            for (int ct = 0; ct < 8; ++ct) {
                short8 bf = *(const short8*)&Wl[(((kk * 8 + ct) * 64) + lane) * 8];
                acc[ct] = __builtin_amdgcn_mfma_f32_16x16x32_bf16(af, bf, acc[ct], 0, 0, 0);
            }
        }
    }

    // epilogue: bias add, store, per-column stats
    #pragma unroll
    for (int ct = 0; ct < 8; ++ct) {
        int col = ct * 16 + n16;
        float bv = __ldg(bias + col);
        float s = 0.f, qs = 0.f;
        #pragma unroll
        for (int reg = 0; reg < 4; ++reg) {
            int row = rowb + q * 4 + reg;
            float v = acc[ct][reg] + bv;
            if (row < N) {
                zout[(size_t)row * D + col] = v;
                s += v;
                qs = fmaf(v, v, qs);
            }
        }
        s  += __shfl_xor(s, 16, 64);
        s  += __shfl_xor(s, 32, 64);
        qs += __shfl_xor(qs, 16, 64);
        qs += __shfl_xor(qs, 32, 64);
        if (lane < 16) {
            part[w * 128 + col] = s;
            part[512 + w * 128 + col] = qs;
        }
    }
    __syncthreads();

    if (tid < 128) {
        float s  = part[tid] + part[128 + tid] + part[256 + tid] + part[384 + tid];
        float qq = part[512 + tid] + part[640 + tid] + part[768 + tid] + part[896 + tid];
        atomicAdd(&stat_sum[tid], s);
        atomicAdd(&stat_sq[tid], qq);
    }
}

// ---------------- BN finalize ----------------
__global__ void bn_finalize_kernel(
    const float* __restrict__ stat_sum, const float* __restrict__ stat_sq,
    const float* __restrict__ gamma, const float* __restrict__ beta,
    float* __restrict__ s_out, float* __restrict__ t_out, float invN)
{
    int c = threadIdx.x;
    float mean = stat_sum[c] * invN;
    float var  = stat_sq[c] * invN - mean * mean;
    float s = gamma[c] * rsqrtf(var + 1e-5f);
    s_out[c] = s;
    t_out[c] = fmaf(-mean, s, beta[c]);
}

// ---------------- final BN + ReLU elementwise ----------------
__global__ __launch_bounds__(256) void bn_relu_kernel(
    const float4* __restrict__ z, float4* __restrict__ out,
    const float* __restrict__ s, const float* __restrict__ t, int total4)
{
    int i = blockIdx.x * 256 + threadIdx.x;
    if (i >= total4) return;
    float4 v = z[i];
    int c = (i & 31) * 4;
    float4 o;
    o.x = fmaxf(fmaf(v.x, s[c + 0], t[c + 0]), 0.f);
    o.y = fmaxf(fmaf(v.y, s[c + 1], t[c + 1]), 0.f);
    o.z = fmaxf(fmaf(v.z, s[c + 2], t[c + 2]), 0.f);
    o.w = fmaxf(fmaf(v.w, s[c + 3], t[c + 3]), 0.f);
    out[i] = o;
}

extern "C" void kernel_launch(void* const* d_in, const int* in_sizes, int n_in,
                              void* d_out, int out_size, void* d_ws, size_t ws_size,
                              hipStream_t stream)
{
    const float* x   = (const float*)d_in[0];
    const int*   ei  = (const int*)d_in[1];
    const float* eps = (const float*)d_in[2];
    const float* W1  = (const float*)d_in[3];
    const float* b1  = (const float*)d_in[4];
    const float* g1  = (const float*)d_in[5];
    const float* be1 = (const float*)d_in[6];
    const float* W2  = (const float*)d_in[7];
    const float* b2  = (const float*)d_in[8];
    const float* g2  = (const float*)d_in[9];
    const float* be2 = (const float*)d_in[10];

    int N = in_sizes[0] / D;       // 50000
    int E = in_sizes[1] / 2;       // 800000

    // workspace layout:
    // region A (N*D floats = 25.6 MB): first half = h0 bf16, second half = xh bf16;
    //   whole region reused as z2 (fp32) by GEMM2 (h0/xh dead by then).
    float* zregion = (float*)d_ws;
    unsigned short* h0bf = (unsigned short*)d_ws;        // N*D ushort
    unsigned short* xh   = h0bf + (size_t)N * D;         // N*D ushort
    float* stats = zregion + (size_t)N * D;              // 1024 floats
    int* counts  = (int*)(stats + 1024);                 // N ints
    int* row_ptr = counts + N;                           // N+1 ints
    int* cursor  = row_ptr + N + 1;                      // N ints
    int* partials= cursor + N;                           // 256 ints
    int* sorted  = partials + 256;                       // E ints
    unsigned short* Wf1 = (unsigned short*)(sorted + E); // 16384 ushort
    unsigned short* Wf2 = Wf1 + 16384;                   // 16384 ushort

    float* sum1 = stats +   0, *sq1 = stats + 128, *s1 = stats + 256, *t1 = stats + 384;
    float* sum2 = stats + 512, *sq2 = stats + 640, *s2 = stats + 768, *t2 = stats + 896;
    float* z1 = (float*)d_out;

    hipMemsetAsync(stats, 0, 1024 * sizeof(float), stream);
    hipMemsetAsync(counts, 0, (size_t)N * sizeof(int), stream);

    int eblocks = (E + 255) / 256;
    int nchunks = (N + SCAN_CHUNK - 1) / SCAN_CHUNK;
    wprep_kernel<<<128, 256, 0, stream>>>(W1, W2, Wf1, Wf2);
    xprep_kernel<<<(N * 32 + 255) / 256, 256, 0, stream>>>(
        (const float4*)x, (uint2*)xh, N * 32);
    hist_kernel<<<eblocks, 256, 0, stream>>>(ei, counts, E);
    partial_sum_kernel<<<nchunks, 256, 0, stream>>>(counts, partials, N);
    scan_partials_kernel<<<1, 256, 0, stream>>>(partials, nchunks, row_ptr, N, E);
    scan_chunk_kernel<<<nchunks, 256, 0, stream>>>(counts, partials, row_ptr, cursor, N);
    fill_kernel<<<eblocks, 256, 0, stream>>>(ei, cursor, sorted, E);
    gather_kernel<<<(N * 64 + 255) / 256, 256, 0, stream>>>(
        (const unsigned*)xh, row_ptr, sorted, eps, (unsigned*)h0bf, N);

    int gblocks = (N + 63) / 64;
    gemm_bn_mfma_kernel<<<gblocks, 256, 0, stream>>>(
        h0bf, nullptr, nullptr, nullptr, Wf1, b1, z1, sum1, sq1, N, 0);
    bn_finalize_kernel<<<1, 128, 0, stream>>>(sum1, sq1, g1, be1, s1, t1, 1.0f / N);
    gemm_bn_mfma_kernel<<<gblocks, 256, 0, stream>>>(
        nullptr, z1, s1, t1, Wf2, b2, zregion, sum2, sq2, N, 1);
    bn_finalize_kernel<<<1, 128, 0, stream>>>(sum2, sq2, g2, be2, s2, t2, 1.0f / N);
    bn_relu_kernel<<<(N * 32 + 255) / 256, 256, 0, stream>>>(
        (const float4*)zregion, (float4*)d_out, s2, t2, N * 32);
}

// Round 6
// 270.103 us; speedup vs baseline: 5.9368x; 1.1462x over previous
//
#include <hip/hip_runtime.h>

#define D 128

typedef __attribute__((ext_vector_type(8))) short short8;
typedef __attribute__((ext_vector_type(4))) float f32x4;

static __device__ __forceinline__ unsigned short f2bf(float f) {
    union { float f; unsigned u; } v; v.f = f;
    unsigned r = v.u + 0x7FFF + ((v.u >> 16) & 1);   // RNE
    return (unsigned short)(r >> 16);
}

static __device__ __forceinline__ float2 bfpair2f(unsigned p) {
    union { unsigned u; float f; } a, b;
    a.u = (p & 0xFFFFu) << 16;
    b.u = p & 0xFFFF0000u;
    return make_float2(a.f, b.f);
}

// ---------------- x -> bf16 row-major ----------------
__global__ __launch_bounds__(256) void xprep_kernel(
    const float4* __restrict__ x4, uint2* __restrict__ xh, int total)
{
    int i = blockIdx.x * 256 + threadIdx.x;
    if (i >= total) return;
    float4 v = x4[i];
    uint2 o;
    o.x = (unsigned)f2bf(v.x) | ((unsigned)f2bf(v.y) << 16);
    o.y = (unsigned)f2bf(v.z) | ((unsigned)f2bf(v.w) << 16);
    xh[i] = o;
}

// -------- linked-list build: two chains per dst (even/odd edge) --------
// head[dst*2 + (e&1)] -> most recent edge; nxt[e] -> previous edge (coalesced write)
__global__ __launch_bounds__(256) void link_build_kernel(
    const int* __restrict__ ei, int* __restrict__ head,
    int* __restrict__ nxt, int E)
{
    int e = blockIdx.x * 256 + threadIdx.x;
    if (e >= E) return;
    int dst = ei[E + e];
    int old = atomicExch(&head[dst * 2 + (e & 1)], e);
    nxt[e] = old;
}

// -------- gather (bf16): h0[n] = bf16((1+eps)*x[n] + sum x[src]) --------
// walks the two chains simultaneously for 2x memory-level parallelism
__global__ __launch_bounds__(256) void gather_kernel(
    const unsigned* __restrict__ xh, const int* __restrict__ head,
    const int* __restrict__ nxt, const int* __restrict__ srcs,
    const float* __restrict__ epsp, unsigned* __restrict__ h0, int N)
{
    int gtid = blockIdx.x * 256 + threadIdx.x;
    int node = gtid >> 6;
    int lane = gtid & 63;
    if (node >= N) return;

    float epsv = 1.0f + __ldg(epsp);
    float2 xv = bfpair2f(xh[(size_t)node * 64 + lane]);
    float ax = epsv * xv.x, ay = epsv * xv.y;

    int e0 = head[node * 2];
    int e1 = head[node * 2 + 1];
    while (e0 >= 0 && e1 >= 0) {
        int n0 = nxt[e0], n1 = nxt[e1];        // chain-dependent loads
        int s0 = srcs[e0], s1 = srcs[e1];      // off-chain
        float2 v0 = bfpair2f(xh[(size_t)s0 * 64 + lane]);
        float2 v1 = bfpair2f(xh[(size_t)s1 * 64 + lane]);
        ax += v0.x + v1.x;
        ay += v0.y + v1.y;
        e0 = n0; e1 = n1;
    }
    while (e0 >= 0) {
        int n0 = nxt[e0]; int s0 = srcs[e0];
        float2 v0 = bfpair2f(xh[(size_t)s0 * 64 + lane]);
        ax += v0.x; ay += v0.y; e0 = n0;
    }
    while (e1 >= 0) {
        int n1 = nxt[e1]; int s1 = srcs[e1];
        float2 v1 = bfpair2f(xh[(size_t)s1 * 64 + lane]);
        ax += v1.x; ay += v1.y; e1 = n1;
    }
    h0[(size_t)node * 64 + lane] =
        (unsigned)f2bf(ax) | ((unsigned)f2bf(ay) << 16);
}

// ---------------- W prep: fp32 [k][n] -> bf16 fragment-ordered ----------------
__global__ __launch_bounds__(256) void wprep_kernel(
    const float* __restrict__ W1, const float* __restrict__ W2,
    unsigned short* __restrict__ Wf1, unsigned short* __restrict__ Wf2)
{
    int idx = blockIdx.x * 256 + threadIdx.x;   // 0..32767
    const float* W = (idx < 16384) ? W1 : W2;
    unsigned short* Wf = (idx < 16384) ? Wf1 : Wf2;
    int e = idx & 16383;
    int j = e & 7, lane = (e >> 3) & 63, ckk = e >> 9;
    int ct = ckk & 7, kk = ckk >> 3;
    int k = kk * 32 + (lane >> 4) * 8 + j;
    int n = ct * 16 + (lane & 15);
    Wf[e] = f2bf(W[k * 128 + n]);
}

// ---------------- MFMA GEMM + BN-stat accumulation ----------------
// mode 0: A = a_bf (bf16 row-major, direct fragment load)
// mode 1: A = bf16(relu(a_f32 * s1[k] + t1[k])), s1/t1 computed in-kernel
//         from stat_in (sum @0, sumsq @128) + gamma/beta (fused finalize)
__global__ __launch_bounds__(256) void gemm_bn_mfma_kernel(
    const unsigned short* __restrict__ a_bf,
    const float* __restrict__ a_f32,
    const float* __restrict__ stat_in, const float* __restrict__ gamma,
    const float* __restrict__ beta, float invN,
    const unsigned short* __restrict__ Wf, const float* __restrict__ bias,
    float* __restrict__ zout,
    float* __restrict__ stat_sum, float* __restrict__ stat_sq,
    int N, int mode)
{
    __shared__ unsigned short Wl[16384];   // 32 KB, fragment-ordered
    __shared__ float part[1024];
    __shared__ float scf[128], shf[128];

    int tid = threadIdx.x;
    {
        float4* dst = (float4*)Wl;
        const float4* srcp = (const float4*)Wf;
        #pragma unroll
        for (int i = 0; i < 8; ++i) dst[tid + i * 256] = srcp[tid + i * 256];
    }
    if (mode == 1 && tid < 128) {          // fused BN1 finalize
        float mean = stat_in[tid] * invN;
        float var  = stat_in[128 + tid] * invN - mean * mean;
        float sv = gamma[tid] * rsqrtf(var + 1e-5f);
        scf[tid] = sv;
        shf[tid] = fmaf(-mean, sv, beta[tid]);
    }
    __syncthreads();

    int w = tid >> 6, lane = tid & 63, q = lane >> 4, n16 = lane & 15;
    int rowb = blockIdx.x * 64 + w * 16;
    int m = rowb + n16;
    int mc = (m < N) ? m : (N - 1);

    f32x4 acc[8];
    #pragma unroll
    for (int ct = 0; ct < 8; ++ct) acc[ct] = (f32x4){0.f, 0.f, 0.f, 0.f};

    if (mode == 0) {
        const unsigned short* arow = a_bf + (size_t)mc * D;
        #pragma unroll
        for (int kk = 0; kk < 4; ++kk) {
            short8 af = *(const short8*)(arow + kk * 32 + q * 8);
            #pragma unroll
            for (int ct = 0; ct < 8; ++ct) {
                short8 bf = *(const short8*)&Wl[(((kk * 8 + ct) * 64) + lane) * 8];
                acc[ct] = __builtin_amdgcn_mfma_f32_16x16x32_bf16(af, bf, acc[ct], 0, 0, 0);
            }
        }
    } else {
        const float* arow = a_f32 + (size_t)mc * D;
        #pragma unroll
        for (int kk = 0; kk < 4; ++kk) {
            int c = kk * 32 + q * 8;
            float4 a0 = *(const float4*)(arow + c);
            float4 a1 = *(const float4*)(arow + c + 4);
            a0.x = fmaxf(fmaf(a0.x, scf[c + 0], shf[c + 0]), 0.f);
            a0.y = fmaxf(fmaf(a0.y, scf[c + 1], shf[c + 1]), 0.f);
            a0.z = fmaxf(fmaf(a0.z, scf[c + 2], shf[c + 2]), 0.f);
            a0.w = fmaxf(fmaf(a0.w, scf[c + 3], shf[c + 3]), 0.f);
            a1.x = fmaxf(fmaf(a1.x, scf[c + 4], shf[c + 4]), 0.f);
            a1.y = fmaxf(fmaf(a1.y, scf[c + 5], shf[c + 5]), 0.f);
            a1.z = fmaxf(fmaf(a1.z, scf[c + 6], shf[c + 6]), 0.f);
            a1.w = fmaxf(fmaf(a1.w, scf[c + 7], shf[c + 7]), 0.f);
            short8 af;
            af[0] = (short)f2bf(a0.x); af[1] = (short)f2bf(a0.y);
            af[2] = (short)f2bf(a0.z); af[3] = (short)f2bf(a0.w);
            af[4] = (short)f2bf(a1.x); af[5] = (short)f2bf(a1.y);
            af[6] = (short)f2bf(a1.z); af[7] = (short)f2bf(a1.w);
            #pragma unroll
            for (int ct = 0; ct < 8; ++ct) {
                short8 bf = *(const short8*)&Wl[(((kk * 8 + ct) * 64) + lane) * 8];
                acc[ct] = __builtin_amdgcn_mfma_f32_16x16x32_bf16(af, bf, acc[ct], 0, 0, 0);
            }
        }
    }

    // epilogue: bias add, store, per-column stats
    #pragma unroll
    for (int ct = 0; ct < 8; ++ct) {
        int col = ct * 16 + n16;
        float bv = __ldg(bias + col);
        float s = 0.f, qs = 0.f;
        #pragma unroll
        for (int reg = 0; reg < 4; ++reg) {
            int row = rowb + q * 4 + reg;
            float v = acc[ct][reg] + bv;
            if (row < N) {
                zout[(size_t)row * D + col] = v;
                s += v;
                qs = fmaf(v, v, qs);
            }
        }
        s  += __shfl_xor(s, 16, 64);
        s  += __shfl_xor(s, 32, 64);
        qs += __shfl_xor(qs, 16, 64);
        qs += __shfl_xor(qs, 32, 64);
        if (lane < 16) {
            part[w * 128 + col] = s;
            part[512 + w * 128 + col] = qs;
        }
    }
    __syncthreads();

    if (tid < 128) {
        float s  = part[tid] + part[128 + tid] + part[256 + tid] + part[384 + tid];
        float qq = part[512 + tid] + part[640 + tid] + part[768 + tid] + part[896 + tid];
        atomicAdd(&stat_sum[tid], s);
        atomicAdd(&stat_sq[tid], qq);
    }
}

// ------------- final BN + ReLU elementwise (fused BN2 finalize) -------------
__global__ __launch_bounds__(256) void bn_relu_kernel(
    const float4* __restrict__ z, float4* __restrict__ out,
    const float* __restrict__ stat2, const float* __restrict__ gamma,
    const float* __restrict__ beta, float invN, int total4)
{
    __shared__ float sf[128], tf[128];
    int tid = threadIdx.x;
    if (tid < 128) {
        float mean = stat2[tid] * invN;
        float var  = stat2[128 + tid] * invN - mean * mean;
        float sv = gamma[tid] * rsqrtf(var + 1e-5f);
        sf[tid] = sv;
        tf[tid] = fmaf(-mean, sv, beta[tid]);
    }
    __syncthreads();

    int i = blockIdx.x * 256 + tid;
    if (i >= total4) return;
    float4 v = z[i];
    int c = (i & 31) * 4;
    float4 o;
    o.x = fmaxf(fmaf(v.x, sf[c + 0], tf[c + 0]), 0.f);
    o.y = fmaxf(fmaf(v.y, sf[c + 1], tf[c + 1]), 0.f);
    o.z = fmaxf(fmaf(v.z, sf[c + 2], tf[c + 2]), 0.f);
    o.w = fmaxf(fmaf(v.w, sf[c + 3], tf[c + 3]), 0.f);
    out[i] = o;
}

extern "C" void kernel_launch(void* const* d_in, const int* in_sizes, int n_in,
                              void* d_out, int out_size, void* d_ws, size_t ws_size,
                              hipStream_t stream)
{
    const float* x   = (const float*)d_in[0];
    const int*   ei  = (const int*)d_in[1];
    const float* eps = (const float*)d_in[2];
    const float* W1  = (const float*)d_in[3];
    const float* b1  = (const float*)d_in[4];
    const float* g1  = (const float*)d_in[5];
    const float* be1 = (const float*)d_in[6];
    const float* W2  = (const float*)d_in[7];
    const float* b2  = (const float*)d_in[8];
    const float* g2  = (const float*)d_in[9];
    const float* be2 = (const float*)d_in[10];

    int N = in_sizes[0] / D;       // 50000
    int E = in_sizes[1] / 2;       // 800000

    // workspace layout:
    // region A (N*D floats = 25.6 MB): first half = h0 bf16, second half = xh bf16;
    //   whole region reused as z2 (fp32) by GEMM2 (h0/xh dead by then).
    float* zregion = (float*)d_ws;
    unsigned short* h0bf = (unsigned short*)d_ws;        // N*D ushort
    unsigned short* xh   = h0bf + (size_t)N * D;         // N*D ushort
    float* stats = zregion + (size_t)N * D;              // 1024 floats (pad)
    int* head    = (int*)(stats + 1024);                 // 2N ints
    int* nxt     = head + 2 * (size_t)N;                 // E ints
    unsigned short* Wf1 = (unsigned short*)(nxt + E);    // 16384 ushort
    unsigned short* Wf2 = Wf1 + 16384;                   // 16384 ushort

    float* sum1 = stats + 0,   *sq1 = stats + 128;
    float* sum2 = stats + 256, *sq2 = stats + 384;
    float* z1 = (float*)d_out;

    hipMemsetAsync(stats, 0, 512 * sizeof(float), stream);
    hipMemsetAsync(head, 0xFF, 2 * (size_t)N * sizeof(int), stream);  // -1 sentinel

    int eblocks = (E + 255) / 256;
    wprep_kernel<<<128, 256, 0, stream>>>(W1, W2, Wf1, Wf2);
    xprep_kernel<<<(N * 32 + 255) / 256, 256, 0, stream>>>(
        (const float4*)x, (uint2*)xh, N * 32);
    link_build_kernel<<<eblocks, 256, 0, stream>>>(ei, head, nxt, E);
    gather_kernel<<<(N * 64 + 255) / 256, 256, 0, stream>>>(
        (const unsigned*)xh, head, nxt, ei, eps, (unsigned*)h0bf, N);

    int gblocks = (N + 63) / 64;
    gemm_bn_mfma_kernel<<<gblocks, 256, 0, stream>>>(
        h0bf, nullptr, nullptr, nullptr, nullptr, 0.f,
        Wf1, b1, z1, sum1, sq1, N, 0);
    gemm_bn_mfma_kernel<<<gblocks, 256, 0, stream>>>(
        nullptr, z1, sum1, g1, be1, 1.0f / N,
        Wf2, b2, zregion, sum2, sq2, N, 1);
    bn_relu_kernel<<<(N * 32 + 255) / 256, 256, 0, stream>>>(
        (const float4*)zregion, (float4*)d_out, sum2, g2, be2, 1.0f / N, N * 32);
}